// Round 3
// baseline (615.455 us; speedup 1.0000x reference)
//
#include <hip/hip_runtime.h>
#include <hip/hip_bf16.h>

typedef __attribute__((ext_vector_type(8))) short short8;
typedef __attribute__((ext_vector_type(4))) short short4v;
typedef __attribute__((ext_vector_type(4))) float f32x4;

#define NR 8192
#define LOG2E 1.4426950408889634f

__device__ __forceinline__ short f2bf(float f) {
  return __builtin_bit_cast(short, __float2bfloat16(f));
}

// ---------------------------------------------------------------------------
// K1: HT2 = (x @ W)^T in bf16, tiled layout HT2[j>>5][f][j&31] (tile =
// 128x32 bf16 = 8 KB). Fused s,t epilogue (log2e folded). ~10 us.
// Also zeroes the 64 per-i-tile semaphores for k_flash's fused reduction
// (same stream => completes before any flash block runs).
// ---------------------------------------------------------------------------
__global__ __launch_bounds__(256) void k_gemm_h(const float* __restrict__ x,
                                                const float* __restrict__ W,
                                                const float* __restrict__ a,
                                                short* __restrict__ HT2,
                                                float* __restrict__ sv,
                                                float* __restrict__ tv,
                                                int* __restrict__ cnt) {
  __shared__ short WT[128][136];  // pad 8 shorts -> 2-way alias (free, m136)
  const int tid = threadIdx.x;
  if (blockIdx.x == 0 && tid < 64) cnt[tid] = 0;
  const int w = tid >> 6;
  const int L = tid & 63;
  const int lm = L & 15;
  const int q = L >> 4;
  const int i0 = blockIdx.x * 64;

  f32x4 acc[8];
#pragma unroll
  for (int nn = 0; nn < 8; ++nn) acc[nn] = (f32x4){0.f, 0.f, 0.f, 0.f};

  for (int kc = 0; kc < 256; kc += 128) {
    if (kc) __syncthreads();
#pragma unroll
    for (int p = 0; p < 16; ++p) {
      int idx = p * 256 + tid;  // 0..4095
      int k = idx >> 5;         // 0..127
      int f4 = (idx & 31) * 4;
      float4 v = *(const float4*)&W[(kc + k) * 128 + f4];
      WT[f4 + 0][k] = f2bf(v.x);
      WT[f4 + 1][k] = f2bf(v.y);
      WT[f4 + 2][k] = f2bf(v.z);
      WT[f4 + 3][k] = f2bf(v.w);
    }
    __syncthreads();
#pragma unroll
    for (int ks = 0; ks < 4; ++ks) {
      int row = i0 + 16 * w + lm;
      const float* xp = &x[(size_t)row * 256 + kc + ks * 32 + q * 8];
      float4 xa = *(const float4*)xp;
      float4 xb = *(const float4*)(xp + 4);
      short8 af;
      af[0] = f2bf(xa.x); af[1] = f2bf(xa.y); af[2] = f2bf(xa.z); af[3] = f2bf(xa.w);
      af[4] = f2bf(xb.x); af[5] = f2bf(xb.y); af[6] = f2bf(xb.z); af[7] = f2bf(xb.w);
#pragma unroll
      for (int nn = 0; nn < 8; ++nn) {
        short8 bf = *(const short8*)&WT[nn * 16 + lm][ks * 32 + q * 8];
        acc[nn] = __builtin_amdgcn_mfma_f32_16x16x32_bf16(af, bf, acc[nn], 0, 0, 0);
      }
    }
  }

  const int ib = i0 + 16 * w + 4 * q;  // this thread's 4 output j-rows
  const int tbase = (ib >> 5) * 4096 + (ib & 31);
  float a1v[8], a2v[8];
#pragma unroll
  for (int nn = 0; nn < 8; ++nn) {
    a1v[nn] = a[nn * 16 + lm];
    a2v[nn] = a[128 + nn * 16 + lm];
  }
  float sr[4] = {0.f, 0.f, 0.f, 0.f};
  float tr[4] = {0.f, 0.f, 0.f, 0.f};
#pragma unroll
  for (int nn = 0; nn < 8; ++nn) {
    int f = nn * 16 + lm;
    short4v o;
    o[0] = f2bf(acc[nn][0]);
    o[1] = f2bf(acc[nn][1]);
    o[2] = f2bf(acc[nn][2]);
    o[3] = f2bf(acc[nn][3]);
    *(short4v*)&HT2[tbase + f * 32] = o;
#pragma unroll
    for (int r = 0; r < 4; ++r) {
      sr[r] += acc[nn][r] * a1v[nn];
      tr[r] += acc[nn][r] * a2v[nn];
    }
  }
#pragma unroll
  for (int d = 1; d < 16; d <<= 1) {
#pragma unroll
    for (int r = 0; r < 4; ++r) {
      sr[r] += __shfl_xor(sr[r], d);
      tr[r] += __shfl_xor(tr[r], d);
    }
  }
  if (lm == 0) {
#pragma unroll
    for (int r = 0; r < 4; ++r) {
      sv[ib + r] = sr[r] * LOG2E;
      tv[ib + r] = tr[r] * LOG2E;
    }
  }
}

// ---------------------------------------------------------------------------
// K3 (R16): R15's LDS-staged flash + FUSED split-j reduction (split-K
// semaphore): all 8 sp-blocks of an i-tile write part/lpart, fence, check in
// on a device-scope atomic counter; the 8th performs the sequential sp=0..7
// reduction (bit-identical order to the old k_reduce) + division + out store.
// Kills the k_reduce dispatch (~8-10 us + launch gap); the reduction tail
// overlaps with still-running flash blocks. Cross-XCD visibility per G16:
// writer __threadfence (wbl2) before atomic, reader __threadfence (inv) after.
// ---------------------------------------------------------------------------
__global__ __launch_bounds__(512, 4) void k_flash(const int* __restrict__ adj,
                                                  const short* __restrict__ HT2,
                                                  const float* __restrict__ sv,
                                                  const float* __restrict__ tv,
                                                  float* __restrict__ part,
                                                  float* __restrict__ lpart,
                                                  int* __restrict__ cnt,
                                                  float* __restrict__ out) {
  __shared__ short lds_s[32768];  // 64 KB: 8 tiles x 8 KB, swizzled
  unsigned* ldsw = (unsigned*)lds_s;
  const int tid = threadIdx.x;
  const int w = tid >> 6;   // 0..7
  const int L = tid & 63;
  const int lm = L & 15;
  const int q = L >> 4;
  const int sp = blockIdx.x & 7;   // j-split (S=8)
  const int it = blockIdx.x >> 3;  // i-tile (64 x 128 rows)
  const int i0 = it * 128;

  const int row0 = i0 + 16 * w + lm;  // each wave: 16 rows
  const float s0 = sv[row0];
  const size_t ar0 = (size_t)row0 * NR;

  f32x4 acc[8];
#pragma unroll
  for (int nn = 0; nn < 8; ++nn) acc[nn] = (f32x4){0.f, 0.f, 0.f, 0.f};
  float l0 = 0.f;

  const int tile0 = sp * 32;  // 32 tiles per split
  // prologue: stage tile0's adj (the only HBM stream in the loop)
  int jb = tile0 * 32 + q * 8;
  int4 sa00 = *(const int4*)&adj[ar0 + jb];
  int4 sa01 = *(const int4*)&adj[ar0 + jb + 4];

  for (int t = 0; t < 32; ++t) {
    if ((t & 7) == 0) {  // stage phase t>>3: 8 tiles -> 64 KB LDS (swizzled)
      __syncthreads();   // prior phase's readers done
      const int pbase_t = tile0 + t;
#pragma unroll
      for (int z = 0; z < 8; ++z) {
        int id = z * 512 + tid;  // 0..4095 uint4s
        int tt = id >> 9;        // tile in phase
        int k = id & 511;
        int f = k >> 2, c = k & 3;
        uint4 v = *(const uint4*)&HT2[(size_t)(pbase_t + tt) * 4096 + k * 8];
        int cs = c ^ ((f >> 1) & 3);
        *(uint4*)&ldsw[tt * 2048 + f * 16 + cs * 4] = v;
      }
      __syncthreads();
    }
    // consume staged adj; prefetch next tile's adj
    int4 a00 = sa00, a01 = sa01;
    if (t + 1 < 32) {
      int jn = (tile0 + t + 1) * 32 + q * 8;
      sa00 = *(const int4*)&adj[ar0 + jn];
      sa01 = *(const int4*)&adj[ar0 + jn + 4];
    }
    const int jc = (tile0 + t) * 32 + q * 8;
    float4 tv0 = *(const float4*)&tv[jc];
    float4 tv1 = *(const float4*)&tv[jc + 4];
    const int tt = t & 7;
    short8 bf[8];
#pragma unroll
    for (int nn = 0; nn < 8; ++nn) {
      int f = nn * 16 + lm;
      bf[nn] = *(const short8*)&ldsw[tt * 2048 + f * 16 + ((q ^ ((f >> 1) & 3)) * 4)];
    }

    int av0[8] = {a00.x, a00.y, a00.z, a00.w, a01.x, a01.y, a01.z, a01.w};
    float tvl[8] = {tv0.x, tv0.y, tv0.z, tv0.w, tv1.x, tv1.y, tv1.z, tv1.w};
    short8 p0;
#pragma unroll
    for (int e = 0; e < 8; ++e) {
      // logits pre-scaled by log2e; lrelu(v) = max(v, 0.2v)
      float v0 = s0 + tvl[e];
      float e0 = fmaxf(v0, 0.2f * v0);
      float pp0 = (av0[e] > 0) ? __builtin_amdgcn_exp2f(e0) : 0.f;
      l0 += pp0;
      p0[e] = f2bf(pp0);
    }
#pragma unroll
    for (int nn = 0; nn < 8; ++nn)
      acc[nn] = __builtin_amdgcn_mfma_f32_16x16x32_bf16(p0, bf[nn], acc[nn], 0, 0, 0);
  }
  __syncthreads();  // slice LDS free -> reuse for epilogue

  // epilogue: wave-private LDS transpose (8 KB/wave = 64 KB), contiguous
  // float4 stores. Single-wave region: lgkmcnt orders, no barrier.
  float* my = (float*)lds_s + w * 2048;
#pragma unroll
  for (int nn = 0; nn < 8; ++nn)
#pragma unroll
    for (int r = 0; r < 4; ++r)
      my[(4 * q + r) * 128 + nn * 16 + lm] = acc[nn][r];
  float* pbase = part + ((size_t)sp * NR + i0 + 16 * w) * 128;
#pragma unroll
  for (int c = 0; c < 8; ++c) {
    int idx = (c * 64 + L) * 4;
    *(float4*)&pbase[idx] = *(const float4*)&my[idx];
  }

  // denominator: reduce the 4 q-replicas of each row
  l0 += __shfl_xor(l0, 16);
  l0 += __shfl_xor(l0, 32);
  if (q == 0) lpart[sp * NR + row0] = l0;

  // ---- fused split-j reduction: last block of this i-tile reduces ----
  __threadfence();   // each thread: make its part/lpart stores device-visible
  __syncthreads();   // all 8 waves' fences retired before publish
  volatile int* flagp = (volatile int*)lds_s;
  if (tid == 0) *flagp = (atomicAdd(&cnt[it], 1) == 7) ? 1 : 0;
  __syncthreads();
  if (*flagp == 0) return;
  __threadfence();   // acquire: invalidate caches, see other XCDs' slices

  const size_t pb = (size_t)i0 * 128;
#pragma unroll
  for (int c = 0; c < 8; ++c) {
    int e = (c * 512 + tid) * 4;  // 0..16380 within this i-tile
    int r = e >> 7;
    f32x4 sum = (f32x4){0.f, 0.f, 0.f, 0.f};
    float l = 0.f;
#pragma unroll
    for (int spp = 0; spp < 8; ++spp) {  // sequential: bit-identical to k_reduce
      const f32x4 v = *(const f32x4*)&part[(size_t)spp * (NR * 128) + pb + e];
      sum[0] += v[0]; sum[1] += v[1]; sum[2] += v[2]; sum[3] += v[3];
      l += lpart[spp * NR + i0 + r];
    }
    float inv = (l > 0.f) ? 1.f / l : 0.f;
    f32x4 o;
    o[0] = sum[0] * inv; o[1] = sum[1] * inv; o[2] = sum[2] * inv; o[3] = sum[3] * inv;
    *(f32x4*)&out[pb + e] = o;
  }
}

extern "C" void kernel_launch(void* const* d_in, const int* in_sizes, int n_in,
                              void* d_out, int out_size, void* d_ws, size_t ws_size,
                              hipStream_t stream) {
  const float* x = (const float*)d_in[0];    // 8192 x 256 fp32
  const int* adj = (const int*)d_in[1];      // 8192 x 8192 int32
  const float* W = (const float*)d_in[2];    // 256 x 128 fp32
  const float* a = (const float*)d_in[3];    // 256 x 1 fp32
  float* out = (float*)d_out;                // 8192 x 128 fp32

  char* ws = (char*)d_ws;
  short* HT2 = (short*)(ws + 0);          // 2 MB  bf16 h tiled [256][128][32]
  float* sv = (float*)(ws + 2097152);     // 32 KB (pre-scaled by log2e)
  float* tv = (float*)(ws + 2129920);     // 32 KB
  float* lpart = (float*)(ws + 2162688);  // 8*32 KB = 256 KB
  float* part = (float*)(ws + 2424832);   // 8 * 4 MB = 32 MB
  int* cnt = (int*)(ws + 35979264);       // 64 i-tile semaphores (256 B)

  const int S = 8;  // j-splits: 64 i-tiles x 8 = 512 blocks of 8 waves

  hipLaunchKernelGGL(k_gemm_h, dim3(128), dim3(256), 0, stream, x, W, a, HT2, sv, tv,
                     cnt);
  hipLaunchKernelGGL(k_flash, dim3(64 * S), dim3(512), 0, stream, adj, HT2, sv, tv,
                     part, lpart, cnt, out);
}

// Round 4
// 418.974 us; speedup vs baseline: 1.4690x; 1.4690x over previous
//
#include <hip/hip_runtime.h>
#include <hip/hip_bf16.h>

typedef __attribute__((ext_vector_type(8))) short short8;
typedef __attribute__((ext_vector_type(4))) short short4v;
typedef __attribute__((ext_vector_type(4))) float f32x4;

typedef const __attribute__((address_space(1))) unsigned gcu32;
typedef __attribute__((address_space(3))) unsigned lu32;

#define NR 8192
#define LOG2E 1.4426950408889634f

__device__ __forceinline__ short f2bf(float f) {
  return __builtin_bit_cast(short, __float2bfloat16(f));
}

// ---------------------------------------------------------------------------
// K1: HT2 = (x @ W)^T in bf16, tiled layout HT2[j>>5][f][j&31] (tile =
// 128x32 bf16 = 8 KB). Fused s,t epilogue (log2e folded). ~10 us.
// ---------------------------------------------------------------------------
__global__ __launch_bounds__(256) void k_gemm_h(const float* __restrict__ x,
                                                const float* __restrict__ W,
                                                const float* __restrict__ a,
                                                short* __restrict__ HT2,
                                                float* __restrict__ sv,
                                                float* __restrict__ tv) {
  __shared__ short WT[128][136];  // pad 8 shorts -> 2-way alias (free, m136)
  const int tid = threadIdx.x;
  const int w = tid >> 6;
  const int L = tid & 63;
  const int lm = L & 15;
  const int q = L >> 4;
  const int i0 = blockIdx.x * 64;

  f32x4 acc[8];
#pragma unroll
  for (int nn = 0; nn < 8; ++nn) acc[nn] = (f32x4){0.f, 0.f, 0.f, 0.f};

  for (int kc = 0; kc < 256; kc += 128) {
    if (kc) __syncthreads();
#pragma unroll
    for (int p = 0; p < 16; ++p) {
      int idx = p * 256 + tid;  // 0..4095
      int k = idx >> 5;         // 0..127
      int f4 = (idx & 31) * 4;
      float4 v = *(const float4*)&W[(kc + k) * 128 + f4];
      WT[f4 + 0][k] = f2bf(v.x);
      WT[f4 + 1][k] = f2bf(v.y);
      WT[f4 + 2][k] = f2bf(v.z);
      WT[f4 + 3][k] = f2bf(v.w);
    }
    __syncthreads();
#pragma unroll
    for (int ks = 0; ks < 4; ++ks) {
      int row = i0 + 16 * w + lm;
      const float* xp = &x[(size_t)row * 256 + kc + ks * 32 + q * 8];
      float4 xa = *(const float4*)xp;
      float4 xb = *(const float4*)(xp + 4);
      short8 af;
      af[0] = f2bf(xa.x); af[1] = f2bf(xa.y); af[2] = f2bf(xa.z); af[3] = f2bf(xa.w);
      af[4] = f2bf(xb.x); af[5] = f2bf(xb.y); af[6] = f2bf(xb.z); af[7] = f2bf(xb.w);
#pragma unroll
      for (int nn = 0; nn < 8; ++nn) {
        short8 bf = *(const short8*)&WT[nn * 16 + lm][ks * 32 + q * 8];
        acc[nn] = __builtin_amdgcn_mfma_f32_16x16x32_bf16(af, bf, acc[nn], 0, 0, 0);
      }
    }
  }

  const int ib = i0 + 16 * w + 4 * q;  // this thread's 4 output j-rows
  const int tbase = (ib >> 5) * 4096 + (ib & 31);
  float a1v[8], a2v[8];
#pragma unroll
  for (int nn = 0; nn < 8; ++nn) {
    a1v[nn] = a[nn * 16 + lm];
    a2v[nn] = a[128 + nn * 16 + lm];
  }
  float sr[4] = {0.f, 0.f, 0.f, 0.f};
  float tr[4] = {0.f, 0.f, 0.f, 0.f};
#pragma unroll
  for (int nn = 0; nn < 8; ++nn) {
    int f = nn * 16 + lm;
    short4v o;
    o[0] = f2bf(acc[nn][0]);
    o[1] = f2bf(acc[nn][1]);
    o[2] = f2bf(acc[nn][2]);
    o[3] = f2bf(acc[nn][3]);
    *(short4v*)&HT2[tbase + f * 32] = o;
#pragma unroll
    for (int r = 0; r < 4; ++r) {
      sr[r] += acc[nn][r] * a1v[nn];
      tr[r] += acc[nn][r] * a2v[nn];
    }
  }
#pragma unroll
  for (int d = 1; d < 16; d <<= 1) {
#pragma unroll
    for (int r = 0; r < 4; ++r) {
      sr[r] += __shfl_xor(sr[r], d);
      tr[r] += __shfl_xor(tr[r], d);
    }
  }
  if (lm == 0) {
#pragma unroll
    for (int r = 0; r < 4; ++r) {
      sv[ib + r] = sr[r] * LOG2E;
      tv[ib + r] = tr[r] * LOG2E;
    }
  }
}

// ---------------------------------------------------------------------------
// K3 (R17): R0's proven S=16 structure (415.3 us measured; S=8 was +16us,
// fused-semaphore was +200us — L2-writeback fence per block, never again).
// One change vs R0: HT2 staging now uses global_load_lds width=16 with the
// XOR swizzle moved to the per-lane GLOBAL source address (m173 pattern;
// LDS dest linear = wave base + lane*16). Deletes 8 uint4 reg-loads +
// 8 ds_write_b128 + index VALU per thread from the barrier-bounded staging
// section. Content mapping bit-identical: slot (f, cd) holds chunk
// cd ^ s(f), reader at cd = q ^ s(f) gets chunk q.
// ---------------------------------------------------------------------------
__global__ __launch_bounds__(512, 4) void k_flash(const int* __restrict__ adj,
                                                  const short* __restrict__ HT2,
                                                  const float* __restrict__ sv,
                                                  const float* __restrict__ tv,
                                                  float* __restrict__ part,
                                                  float* __restrict__ lpart) {
  __shared__ short lds_s[32768];  // 64 KB: 8 tiles x 8 KB, swizzled
  unsigned* ldsw = (unsigned*)lds_s;
  const int tid = threadIdx.x;
  const int w = tid >> 6;   // 0..7
  const int L = tid & 63;
  const int lm = L & 15;
  const int q = L >> 4;
  const int sp = blockIdx.x & 15;  // j-split (S=16)
  const int it = blockIdx.x >> 4;  // i-tile (64 x 128 rows)
  const int i0 = it * 128;

  const int row0 = i0 + 16 * w + lm;  // each wave: 16 rows
  const float s0 = sv[row0];
  const size_t ar0 = (size_t)row0 * NR;

  // source-swizzled chunk index for global_load_lds staging:
  // lane tid fills linear LDS slot (f=tid>>2, cd=tid&3) with global chunk
  // (f*4) | (cd ^ s(f)), s(f) = (f>>1)&3 = (tid>>3)&3.
  const int ksrc = (tid & 0x1FC) | ((tid & 3) ^ ((tid >> 3) & 3));

  f32x4 acc[8];
#pragma unroll
  for (int nn = 0; nn < 8; ++nn) acc[nn] = (f32x4){0.f, 0.f, 0.f, 0.f};
  float l0 = 0.f;

  const int tile0 = sp * 16;  // 16 tiles per split
  // prologue: stage tile0's adj (the only HBM stream in the loop)
  int jb = tile0 * 32 + q * 8;
  int4 sa00 = *(const int4*)&adj[ar0 + jb];
  int4 sa01 = *(const int4*)&adj[ar0 + jb + 4];

  for (int t = 0; t < 16; ++t) {
    if ((t & 7) == 0) {  // stage phase t>>3: 8 tiles -> 64 KB LDS
      __syncthreads();   // prior phase's readers done
      const short* gs = &HT2[(size_t)(tile0 + t) * 4096 + ksrc * 8];
#pragma unroll
      for (int z = 0; z < 8; ++z)
        __builtin_amdgcn_global_load_lds((gcu32*)(gs + z * 4096),
                                         (lu32*)&ldsw[z * 2048 + w * 256], 16, 0, 0);
      __syncthreads();   // compiler drains vmcnt(0) before barrier
    }
    // consume staged adj; prefetch next tile's adj
    int4 a00 = sa00, a01 = sa01;
    if (t + 1 < 16) {
      int jn = (tile0 + t + 1) * 32 + q * 8;
      sa00 = *(const int4*)&adj[ar0 + jn];
      sa01 = *(const int4*)&adj[ar0 + jn + 4];
    }
    const int jc = (tile0 + t) * 32 + q * 8;
    float4 tv0 = *(const float4*)&tv[jc];
    float4 tv1 = *(const float4*)&tv[jc + 4];
    const int tt = t & 7;
    short8 bf[8];
#pragma unroll
    for (int nn = 0; nn < 8; ++nn) {
      int f = nn * 16 + lm;
      bf[nn] = *(const short8*)&ldsw[tt * 2048 + f * 16 + ((q ^ ((f >> 1) & 3)) * 4)];
    }

    int av0[8] = {a00.x, a00.y, a00.z, a00.w, a01.x, a01.y, a01.z, a01.w};
    float tvl[8] = {tv0.x, tv0.y, tv0.z, tv0.w, tv1.x, tv1.y, tv1.z, tv1.w};
    short8 p0;
#pragma unroll
    for (int e = 0; e < 8; ++e) {
      // logits pre-scaled by log2e; lrelu(v) = max(v, 0.2v)
      float v0 = s0 + tvl[e];
      float e0 = fmaxf(v0, 0.2f * v0);
      float pp0 = (av0[e] > 0) ? __builtin_amdgcn_exp2f(e0) : 0.f;
      l0 += pp0;
      p0[e] = f2bf(pp0);
    }
#pragma unroll
    for (int nn = 0; nn < 8; ++nn)
      acc[nn] = __builtin_amdgcn_mfma_f32_16x16x32_bf16(p0, bf[nn], acc[nn], 0, 0, 0);
  }
  __syncthreads();  // slice LDS free -> reuse for epilogue

  // epilogue: wave-private LDS transpose (8 KB/wave = 64 KB), contiguous
  // float4 stores. Single-wave region: lgkmcnt orders, no barrier.
  float* my = (float*)lds_s + w * 2048;
#pragma unroll
  for (int nn = 0; nn < 8; ++nn)
#pragma unroll
    for (int r = 0; r < 4; ++r)
      my[(4 * q + r) * 128 + nn * 16 + lm] = acc[nn][r];
  float* pbase = part + ((size_t)sp * NR + i0 + 16 * w) * 128;
#pragma unroll
  for (int c = 0; c < 8; ++c) {
    int idx = (c * 64 + L) * 4;
    *(float4*)&pbase[idx] = *(const float4*)&my[idx];
  }

  // denominator: reduce the 4 q-replicas of each row
  l0 += __shfl_xor(l0, 16);
  l0 += __shfl_xor(l0, 32);
  if (q == 0) lpart[sp * NR + row0] = l0;
}

// ---------------------------------------------------------------------------
// K4: out[i][f] = sum_sp part / sum_sp lpart   (float4 vectorized)
// ---------------------------------------------------------------------------
__global__ __launch_bounds__(256) void k_reduce(const float* __restrict__ part,
                                                const float* __restrict__ lpart,
                                                float* __restrict__ out, int S) {
  int idx4 = blockIdx.x * 256 + threadIdx.x;
  int idx = idx4 * 4;  // i*128+f
  int i = idx >> 7;
  float4 sum = {0.f, 0.f, 0.f, 0.f};
  for (int sp = 0; sp < S; ++sp) {
    float4 v = *(const float4*)&part[(size_t)sp * (NR * 128) + idx];
    sum.x += v.x; sum.y += v.y; sum.z += v.z; sum.w += v.w;
  }
  float l = 0.f;
  for (int sp = 0; sp < S; ++sp) l += lpart[sp * NR + i];
  float inv = (l > 0.f) ? 1.f / l : 0.f;
  float4 o = {sum.x * inv, sum.y * inv, sum.z * inv, sum.w * inv};
  *(float4*)&out[idx] = o;
}

extern "C" void kernel_launch(void* const* d_in, const int* in_sizes, int n_in,
                              void* d_out, int out_size, void* d_ws, size_t ws_size,
                              hipStream_t stream) {
  const float* x = (const float*)d_in[0];    // 8192 x 256 fp32
  const int* adj = (const int*)d_in[1];      // 8192 x 8192 int32
  const float* W = (const float*)d_in[2];    // 256 x 128 fp32
  const float* a = (const float*)d_in[3];    // 256 x 1 fp32
  float* out = (float*)d_out;                // 8192 x 128 fp32

  char* ws = (char*)d_ws;
  short* HT2 = (short*)(ws + 0);          // 2 MB  bf16 h tiled [256][128][32]
  float* sv = (float*)(ws + 2097152);     // 32 KB (pre-scaled by log2e)
  float* tv = (float*)(ws + 2129920);     // 32 KB
  float* lpart = (float*)(ws + 2162688);  // 16*32 KB = 512 KB
  float* part = (float*)(ws + 2719744);   // 16 * 4 MB = 64 MB

  const int S = 16;  // j-splits: 64 i-tiles x 16 = 1024 blocks of 8 waves

  hipLaunchKernelGGL(k_gemm_h, dim3(128), dim3(256), 0, stream, x, W, a, HT2, sv, tv);
  hipLaunchKernelGGL(k_flash, dim3(64 * S), dim3(512), 0, stream, adj, HT2, sv, tv,
                     part, lpart);
  hipLaunchKernelGGL(k_reduce, dim3((NR * 128) / 1024), dim3(256), 0, stream, part,
                     lpart, out, S);
}

// Round 5
// 415.745 us; speedup vs baseline: 1.4804x; 1.0078x over previous
//
#include <hip/hip_runtime.h>
#include <hip/hip_bf16.h>

typedef __attribute__((ext_vector_type(8))) short short8;
typedef __attribute__((ext_vector_type(4))) short short4v;
typedef __attribute__((ext_vector_type(4))) float f32x4;

typedef const __attribute__((address_space(1))) unsigned gcu32;
typedef __attribute__((address_space(3))) unsigned lu32;

#define NR 8192
#define LOG2E 1.4426950408889634f

__device__ __forceinline__ short f2bf(float f) {
  return __builtin_bit_cast(short, __float2bfloat16(f));
}
__device__ __forceinline__ float bf2f(short s) {
  return __builtin_bit_cast(float, ((unsigned)(unsigned short)s) << 16);
}

// ---------------------------------------------------------------------------
// K1: HT2 = (x @ W)^T in bf16, tiled layout HT2[j>>5][f][j&31] (tile =
// 128x32 bf16 = 8 KB). Fused s,t epilogue (log2e folded). ~10 us. Unchanged.
// ---------------------------------------------------------------------------
__global__ __launch_bounds__(256) void k_gemm_h(const float* __restrict__ x,
                                                const float* __restrict__ W,
                                                const float* __restrict__ a,
                                                short* __restrict__ HT2,
                                                float* __restrict__ sv,
                                                float* __restrict__ tv) {
  __shared__ short WT[128][136];  // pad 8 shorts -> 2-way alias (free, m136)
  const int tid = threadIdx.x;
  const int w = tid >> 6;
  const int L = tid & 63;
  const int lm = L & 15;
  const int q = L >> 4;
  const int i0 = blockIdx.x * 64;

  f32x4 acc[8];
#pragma unroll
  for (int nn = 0; nn < 8; ++nn) acc[nn] = (f32x4){0.f, 0.f, 0.f, 0.f};

  for (int kc = 0; kc < 256; kc += 128) {
    if (kc) __syncthreads();
#pragma unroll
    for (int p = 0; p < 16; ++p) {
      int idx = p * 256 + tid;  // 0..4095
      int k = idx >> 5;         // 0..127
      int f4 = (idx & 31) * 4;
      float4 v = *(const float4*)&W[(kc + k) * 128 + f4];
      WT[f4 + 0][k] = f2bf(v.x);
      WT[f4 + 1][k] = f2bf(v.y);
      WT[f4 + 2][k] = f2bf(v.z);
      WT[f4 + 3][k] = f2bf(v.w);
    }
    __syncthreads();
#pragma unroll
    for (int ks = 0; ks < 4; ++ks) {
      int row = i0 + 16 * w + lm;
      const float* xp = &x[(size_t)row * 256 + kc + ks * 32 + q * 8];
      float4 xa = *(const float4*)xp;
      float4 xb = *(const float4*)(xp + 4);
      short8 af;
      af[0] = f2bf(xa.x); af[1] = f2bf(xa.y); af[2] = f2bf(xa.z); af[3] = f2bf(xa.w);
      af[4] = f2bf(xb.x); af[5] = f2bf(xb.y); af[6] = f2bf(xb.z); af[7] = f2bf(xb.w);
#pragma unroll
      for (int nn = 0; nn < 8; ++nn) {
        short8 bf = *(const short8*)&WT[nn * 16 + lm][ks * 32 + q * 8];
        acc[nn] = __builtin_amdgcn_mfma_f32_16x16x32_bf16(af, bf, acc[nn], 0, 0, 0);
      }
    }
  }

  const int ib = i0 + 16 * w + 4 * q;  // this thread's 4 output j-rows
  const int tbase = (ib >> 5) * 4096 + (ib & 31);
  float a1v[8], a2v[8];
#pragma unroll
  for (int nn = 0; nn < 8; ++nn) {
    a1v[nn] = a[nn * 16 + lm];
    a2v[nn] = a[128 + nn * 16 + lm];
  }
  float sr[4] = {0.f, 0.f, 0.f, 0.f};
  float tr[4] = {0.f, 0.f, 0.f, 0.f};
#pragma unroll
  for (int nn = 0; nn < 8; ++nn) {
    int f = nn * 16 + lm;
    short4v o;
    o[0] = f2bf(acc[nn][0]);
    o[1] = f2bf(acc[nn][1]);
    o[2] = f2bf(acc[nn][2]);
    o[3] = f2bf(acc[nn][3]);
    *(short4v*)&HT2[tbase + f * 32] = o;
#pragma unroll
    for (int r = 0; r < 4; ++r) {
      sr[r] += acc[nn][r] * a1v[nn];
      tr[r] += acc[nn][r] * a2v[nn];
    }
  }
#pragma unroll
  for (int d = 1; d < 16; d <<= 1) {
#pragma unroll
    for (int r = 0; r < 4; ++r) {
      sr[r] += __shfl_xor(sr[r], d);
      tr[r] += __shfl_xor(tr[r], d);
    }
  }
  if (lm == 0) {
#pragma unroll
    for (int r = 0; r < 4; ++r) {
      sv[ib + r] = sr[r] * LOG2E;
      tv[ib + r] = tr[r] * LOG2E;
    }
  }
}

// ---------------------------------------------------------------------------
// K3 (R18): 16-wave blocks (1024 thr, 256 i-rows) double the staged-tile
// sharing factor: HT2 staging traffic 128 MB -> 64 MB (512 blocks x 128 KB).
// part stored bf16 -> part round-trip 128 MB -> 64 MB; epilogue transpose
// shrinks to 4 KB/wave so all 16 waves fit one 64 KB LDS phase.
// Staging slot map: lane slot = z*1024 + tid (16-B units, linear LDS);
// source chunk = swz(tid & 511) in tile z*2 + (tid>>9) — LDS image
// bit-identical to R17's, readers untouched.
// Journal: R14 direct-L2 = 167us (line-rate!); R16 fence-fusion = +200us
// (L2-writeback per block); S=16 beats S=8 by 16us. Line-rate bytes are
// the objective: now adj 256 + HT2 64 + part(w) 32 ~= 352 MB => ~46-48us.
// ---------------------------------------------------------------------------
__global__ __launch_bounds__(1024, 4) void k_flash(const int* __restrict__ adj,
                                                   const short* __restrict__ HT2,
                                                   const float* __restrict__ sv,
                                                   const float* __restrict__ tv,
                                                   short* __restrict__ part,
                                                   float* __restrict__ lpart) {
  __shared__ short lds_s[32768];  // 64 KB: 8 tiles x 8 KB, swizzled
  unsigned* ldsw = (unsigned*)lds_s;
  const int tid = threadIdx.x;
  const int w = tid >> 6;   // 0..15
  const int L = tid & 63;
  const int lm = L & 15;
  const int q = L >> 4;
  const int sp = blockIdx.x & 15;  // j-split (S=16)
  const int it = blockIdx.x >> 4;  // i-tile (32 x 256 rows)
  const int i0 = it * 256;

  const int row0 = i0 + 16 * w + lm;  // each wave: 16 rows
  const float s0 = sv[row0];
  const size_t ar0 = (size_t)row0 * NR;

  // source-swizzled chunk index: within-tile chunk c = tid & 511 holds
  // global chunk (c & ~3) | ((c&3) ^ ((c>>3)&3)); tile = z*2 + (tid>>9).
  const int c511 = tid & 511;
  const int ksrc = (c511 & 0x1FC) | ((c511 & 3) ^ ((c511 >> 3) & 3));
  const int hi = tid >> 9;  // wave-uniform (0 for w<8, 1 for w>=8)

  f32x4 acc[8];
#pragma unroll
  for (int nn = 0; nn < 8; ++nn) acc[nn] = (f32x4){0.f, 0.f, 0.f, 0.f};
  float l0 = 0.f;

  const int tile0 = sp * 16;  // 16 tiles per split
  // prologue: stage tile0's adj (the only HBM stream in the loop)
  int jb = tile0 * 32 + q * 8;
  int4 sa00 = *(const int4*)&adj[ar0 + jb];
  int4 sa01 = *(const int4*)&adj[ar0 + jb + 4];

  for (int t = 0; t < 16; ++t) {
    if ((t & 7) == 0) {  // stage phase t>>3: 8 tiles -> 64 KB LDS
      __syncthreads();   // prior phase's readers done
      const short* gs = &HT2[(size_t)(tile0 + t + hi) * 4096 + ksrc * 8];
#pragma unroll
      for (int z = 0; z < 4; ++z)
        __builtin_amdgcn_global_load_lds((gcu32*)(gs + z * 2 * 4096),
                                         (lu32*)&ldsw[z * 4096 + w * 256], 16, 0, 0);
      __syncthreads();   // compiler drains vmcnt(0) before barrier
    }
    // consume staged adj; prefetch next tile's adj
    int4 a00 = sa00, a01 = sa01;
    if (t + 1 < 16) {
      int jn = (tile0 + t + 1) * 32 + q * 8;
      sa00 = *(const int4*)&adj[ar0 + jn];
      sa01 = *(const int4*)&adj[ar0 + jn + 4];
    }
    const int jc = (tile0 + t) * 32 + q * 8;
    float4 tv0 = *(const float4*)&tv[jc];
    float4 tv1 = *(const float4*)&tv[jc + 4];
    const int tt = t & 7;
    short8 bf[8];
#pragma unroll
    for (int nn = 0; nn < 8; ++nn) {
      int f = nn * 16 + lm;
      bf[nn] = *(const short8*)&ldsw[tt * 2048 + f * 16 + ((q ^ ((f >> 1) & 3)) * 4)];
    }

    int av0[8] = {a00.x, a00.y, a00.z, a00.w, a01.x, a01.y, a01.z, a01.w};
    float tvl[8] = {tv0.x, tv0.y, tv0.z, tv0.w, tv1.x, tv1.y, tv1.z, tv1.w};
    short8 p0;
#pragma unroll
    for (int e = 0; e < 8; ++e) {
      // logits pre-scaled by log2e; lrelu(v) = max(v, 0.2v)
      float v0 = s0 + tvl[e];
      float e0 = fmaxf(v0, 0.2f * v0);
      float pp0 = (av0[e] > 0) ? __builtin_amdgcn_exp2f(e0) : 0.f;
      l0 += pp0;
      p0[e] = f2bf(pp0);
    }
#pragma unroll
    for (int nn = 0; nn < 8; ++nn)
      acc[nn] = __builtin_amdgcn_mfma_f32_16x16x32_bf16(p0, bf[nn], acc[nn], 0, 0, 0);
  }
  __syncthreads();  // staging LDS free -> reuse for epilogue

  // epilogue: wave-private LDS transpose in bf16 (4 KB/wave x 16 = 64 KB),
  // contiguous uint4 stores. Single-wave region: lgkmcnt orders, no barrier.
  short* my = lds_s + w * 2048;  // 2048 shorts = 4 KB
#pragma unroll
  for (int nn = 0; nn < 8; ++nn)
#pragma unroll
    for (int r = 0; r < 4; ++r)
      my[(4 * q + r) * 128 + nn * 16 + lm] = f2bf(acc[nn][r]);
  short* pb = part + ((size_t)sp * NR + i0 + 16 * w) * 128;
#pragma unroll
  for (int c = 0; c < 4; ++c) {
    int idx = (c * 64 + L) * 8;  // shorts, 16-B aligned
    *(uint4*)&pb[idx] = *(const uint4*)&my[idx];
  }

  // denominator: reduce the 4 q-replicas of each row (fp32, exact)
  l0 += __shfl_xor(l0, 16);
  l0 += __shfl_xor(l0, 32);
  if (q == 0) lpart[sp * NR + row0] = l0;
}

// ---------------------------------------------------------------------------
// K4: out[i][f] = sum_sp part(bf16) / sum_sp lpart(f32)
// ---------------------------------------------------------------------------
__global__ __launch_bounds__(256) void k_reduce(const short* __restrict__ part,
                                                const float* __restrict__ lpart,
                                                float* __restrict__ out, int S) {
  int idx4 = blockIdx.x * 256 + threadIdx.x;
  int idx = idx4 * 4;  // i*128+f
  int i = idx >> 7;
  float4 sum = {0.f, 0.f, 0.f, 0.f};
  for (int sp = 0; sp < S; ++sp) {
    short4v v = *(const short4v*)&part[(size_t)sp * (NR * 128) + idx];
    sum.x += bf2f(v[0]); sum.y += bf2f(v[1]);
    sum.z += bf2f(v[2]); sum.w += bf2f(v[3]);
  }
  float l = 0.f;
  for (int sp = 0; sp < S; ++sp) l += lpart[sp * NR + i];
  float inv = (l > 0.f) ? 1.f / l : 0.f;
  float4 o = {sum.x * inv, sum.y * inv, sum.z * inv, sum.w * inv};
  *(float4*)&out[idx] = o;
}

extern "C" void kernel_launch(void* const* d_in, const int* in_sizes, int n_in,
                              void* d_out, int out_size, void* d_ws, size_t ws_size,
                              hipStream_t stream) {
  const float* x = (const float*)d_in[0];    // 8192 x 256 fp32
  const int* adj = (const int*)d_in[1];      // 8192 x 8192 int32
  const float* W = (const float*)d_in[2];    // 256 x 128 fp32
  const float* a = (const float*)d_in[3];    // 256 x 1 fp32
  float* out = (float*)d_out;                // 8192 x 128 fp32

  char* ws = (char*)d_ws;
  short* HT2 = (short*)(ws + 0);          // 2 MB  bf16 h tiled [256][128][32]
  float* sv = (float*)(ws + 2097152);     // 32 KB (pre-scaled by log2e)
  float* tv = (float*)(ws + 2129920);     // 32 KB
  float* lpart = (float*)(ws + 2162688);  // 16*32 KB = 512 KB
  short* part = (short*)(ws + 2719744);   // 16 * 2 MB = 32 MB (bf16)

  const int S = 16;  // j-splits: 32 i-tiles x 16 = 512 blocks of 16 waves

  hipLaunchKernelGGL(k_gemm_h, dim3(128), dim3(256), 0, stream, x, W, a, HT2, sv, tv);
  hipLaunchKernelGGL(k_flash, dim3(32 * S), dim3(1024), 0, stream, adj, HT2, sv, tv,
                     part, lpart);
  hipLaunchKernelGGL(k_reduce, dim3((NR * 128) / 1024), dim3(256), 0, stream, part,
                     lpart, out, S);
}